// Round 1
// baseline (2409.153 us; speedup 1.0000x reference)
//
#include <hip/hip_runtime.h>
#include <hip/hip_bf16.h>
#include <math.h>

#define Bsz 2
#define Lsz 1024
#define Dsz 1024
#define Hsz 16
#define Dh 64
#define Mtot (Bsz*Lsz)   // 2048

// ---------------- fp32 tiled SGEMM: C = A @ W + bias ----------------
// A: M x K row-major, W: K x N row-major, C: M x N. BM=BN=128, BK=8.
// 256 threads, each computes 8x8.
__global__ __launch_bounds__(256) void sgemm_kernel(
    const float* __restrict__ A, const float* __restrict__ W,
    const float* __restrict__ bias, float* __restrict__ C,
    int Mdim, int Ndim, int Kdim)
{
    __shared__ float As[8][128];
    __shared__ float Bs[8][132];   // +4 pad
    const int tid = threadIdx.x;
    const int row0 = blockIdx.x * 128;
    const int col0 = blockIdx.y * 128;
    const int tx = tid & 15;       // 0..15 -> col group
    const int ty = tid >> 4;       // 0..15 -> row group
    const int arow = tid >> 1;         // 0..127
    const int acol = (tid & 1) * 4;    // 0 or 4
    const int brow = tid >> 5;         // 0..7
    const int bcol = (tid & 31) * 4;   // 0..124

    float acc[8][8];
    #pragma unroll
    for (int i = 0; i < 8; ++i)
        #pragma unroll
        for (int j = 0; j < 8; ++j) acc[i][j] = 0.f;

    for (int k0 = 0; k0 < Kdim; k0 += 8) {
        float4 av = *reinterpret_cast<const float4*>(&A[(size_t)(row0 + arow) * Kdim + k0 + acol]);
        float4 bv = *reinterpret_cast<const float4*>(&W[(size_t)(k0 + brow) * Ndim + col0 + bcol]);
        As[acol + 0][arow] = av.x;
        As[acol + 1][arow] = av.y;
        As[acol + 2][arow] = av.z;
        As[acol + 3][arow] = av.w;
        *reinterpret_cast<float4*>(&Bs[brow][bcol]) = bv;
        __syncthreads();
        #pragma unroll
        for (int k = 0; k < 8; ++k) {
            float4 a0 = *reinterpret_cast<const float4*>(&As[k][ty * 8]);
            float4 a1 = *reinterpret_cast<const float4*>(&As[k][ty * 8 + 4]);
            float4 b0 = *reinterpret_cast<const float4*>(&Bs[k][tx * 8]);
            float4 b1 = *reinterpret_cast<const float4*>(&Bs[k][tx * 8 + 4]);
            float a[8]  = {a0.x, a0.y, a0.z, a0.w, a1.x, a1.y, a1.z, a1.w};
            float bb[8] = {b0.x, b0.y, b0.z, b0.w, b1.x, b1.y, b1.z, b1.w};
            #pragma unroll
            for (int i = 0; i < 8; ++i)
                #pragma unroll
                for (int j = 0; j < 8; ++j)
                    acc[i][j] += a[i] * bb[j];
        }
        __syncthreads();
    }

    const int crow = row0 + ty * 8;
    const int ccol = col0 + tx * 8;
    float bloc[8];
    #pragma unroll
    for (int j = 0; j < 8; ++j) bloc[j] = bias[ccol + j];
    #pragma unroll
    for (int i = 0; i < 8; ++i) {
        float4 o0, o1;
        o0.x = acc[i][0] + bloc[0]; o0.y = acc[i][1] + bloc[1];
        o0.z = acc[i][2] + bloc[2]; o0.w = acc[i][3] + bloc[3];
        o1.x = acc[i][4] + bloc[4]; o1.y = acc[i][5] + bloc[5];
        o1.z = acc[i][6] + bloc[6]; o1.w = acc[i][7] + bloc[7];
        *reinterpret_cast<float4*>(&C[(size_t)(crow + i) * Ndim + ccol])     = o0;
        *reinterpret_cast<float4*>(&C[(size_t)(crow + i) * Ndim + ccol + 4]) = o1;
    }
}

// ---------------- sequential dual-branch scan ----------------
// One workgroup per (b,h). 256 threads = 4 waves.
// lane e = tid & 63 owns state column e; wave w = tid>>6 owns d in [16w,16w+16).
// S1[d][e] += K[d]*V[e]; O1[e] = sum_d Q[d]*S1[d][e]
// E[e] = x_raw[l+1][e] - O1[e]; k2[d]=sigmoid(z[d]*0.02/32); q2[d]=f(Q[d])
// S2[d][e] += k2[d]*E[e]; O2next[e] = sum_d q2[d]*S2[d][e]
// y[l] = O1[l] + O2prev; O2prev <- O2next
__global__ __launch_bounds__(256) void scan_kernel(
    const float* __restrict__ Q, const float* __restrict__ K,
    const float* __restrict__ V, const float* __restrict__ Z,
    const float* __restrict__ x, float* __restrict__ y)
{
    const int bh = blockIdx.x;
    const int b = bh >> 4;
    const int h = bh & 15;
    const int tid = threadIdx.x;
    const int lane = tid & 63;
    const int w = tid >> 6;
    const int d0 = w * 16;

    __shared__ float kbuf[64], vbuf[64], qbuf[64], zbuf[64], xbuf[64];
    __shared__ float red1[4][64], red2[4][64];
    __shared__ float ebuf[64], o2prev[64];

    float s1[16], s2[16];
    #pragma unroll
    for (int i = 0; i < 16; ++i) { s1[i] = 0.f; s2[i] = 0.f; }
    if (tid < 64) o2prev[tid] = 0.f;

    const size_t base = ((size_t)b * Lsz) * Dsz + (size_t)h * Dh;
    __syncthreads();

    for (int l = 0; l < Lsz; ++l) {
        const size_t off = base + (size_t)l * Dsz;
        // stage this step's vectors
        if (tid < 64) {
            kbuf[tid] = K[off + tid];
            zbuf[tid] = Z[off + tid];
        } else if (tid < 128) {
            vbuf[tid - 64] = V[off + (tid - 64)];
        } else if (tid < 192) {
            qbuf[tid - 128] = Q[off + (tid - 128)];
        } else {
            if (l < Lsz - 1) xbuf[tid - 192] = x[off + Dsz + (tid - 192)];
        }
        __syncthreads();   // B1

        // branch 1: state update + matvec partial
        const float v = vbuf[lane];
        float p1 = 0.f;
        #pragma unroll
        for (int i = 0; i < 16; ++i) {
            s1[i] += kbuf[d0 + i] * v;
            p1 += qbuf[d0 + i] * s1[i];
        }
        red1[w][lane] = p1;
        __syncthreads();   // B2

        if (tid < 64) {
            const float o1 = red1[0][tid] + red1[1][tid] + red1[2][tid] + red1[3][tid];
            y[off + tid] = o1 + o2prev[tid];
            ebuf[tid] = xbuf[tid] - o1;
        }
        __syncthreads();   // B3

        if (l < Lsz - 1) {
            const float e = ebuf[lane];
            float p2 = 0.f;
            #pragma unroll
            for (int i = 0; i < 16; ++i) {
                const float zz = zbuf[d0 + i];
                const float k2 = 1.f / (1.f + __expf(-zz * 0.000625f));
                const float q = qbuf[d0 + i];
                const float q2 = (q >= 0.f ? 0.02f * q : q) * 0.125f;
                s2[i] += k2 * e;
                p2 += q2 * s2[i];
            }
            red2[w][lane] = p2;
            __syncthreads();   // B4
            if (tid < 64)
                o2prev[tid] = red2[0][tid] + red2[1][tid] + red2[2][tid] + red2[3][tid];
            __syncthreads();   // B5
        }
    }
}

extern "C" void kernel_launch(void* const* d_in, const int* in_sizes, int n_in,
                              void* d_out, int out_size, void* d_ws, size_t ws_size,
                              hipStream_t stream) {
    const float* x   = (const float*)d_in[0];
    const float* Wq  = (const float*)d_in[1];
    const float* bq  = (const float*)d_in[2];
    const float* Wk1 = (const float*)d_in[3];
    const float* bk1 = (const float*)d_in[4];
    const float* Wv  = (const float*)d_in[5];
    const float* bv  = (const float*)d_in[6];
    const float* Wk2 = (const float*)d_in[7];
    const float* bk2 = (const float*)d_in[8];
    const float* Wp  = (const float*)d_in[9];
    const float* bp  = (const float*)d_in[10];
    float* out = (float*)d_out;
    float* ws  = (float*)d_ws;

    const size_t mat = (size_t)Mtot * Dsz;   // 2048*1024
    float* Qb = ws;
    float* Kb = ws + mat;
    float* Vb = ws + 2 * mat;
    float* Zb = ws + 3 * mat;
    float* Yb = ws + 4 * mat;

    dim3 grid(Mtot / 128, Dsz / 128);
    dim3 block(256);
    sgemm_kernel<<<grid, block, 0, stream>>>(x, Wq,  bq,  Qb, Mtot, Dsz, Dsz);
    sgemm_kernel<<<grid, block, 0, stream>>>(x, Wk1, bk1, Kb, Mtot, Dsz, Dsz);
    sgemm_kernel<<<grid, block, 0, stream>>>(x, Wv,  bv,  Vb, Mtot, Dsz, Dsz);
    sgemm_kernel<<<grid, block, 0, stream>>>(x, Wk2, bk2, Zb, Mtot, Dsz, Dsz);

    scan_kernel<<<dim3(Bsz * Hsz), block, 0, stream>>>(Qb, Kb, Vb, Zb, x, Yb);

    sgemm_kernel<<<grid, block, 0, stream>>>(Yb, Wp, bp, out, Mtot, Dsz, Dsz);
}

// Round 2
// 889.135 us; speedup vs baseline: 2.7095x; 2.7095x over previous
//
#include <hip/hip_runtime.h>
#include <hip/hip_bf16.h>
#include <math.h>

#define Bsz 2
#define Lsz 1024
#define Dsz 1024
#define Hsz 16
#define Dh 64
#define Mtot (Bsz*Lsz)   // 2048
#define NC (Lsz/64)      // 16 chunks per (b,h)

// ---------------- fp32 tiled SGEMM: C = A @ W + bias ----------------
__global__ __launch_bounds__(256) void sgemm_kernel(
    const float* __restrict__ A, const float* __restrict__ W,
    const float* __restrict__ bias, float* __restrict__ C,
    int Mdim, int Ndim, int Kdim)
{
    __shared__ float As[8][128];
    __shared__ float Bs[8][132];
    const int tid = threadIdx.x;
    const int row0 = blockIdx.x * 128;
    const int col0 = blockIdx.y * 128;
    const int tx = tid & 15;
    const int ty = tid >> 4;
    const int arow = tid >> 1;
    const int acol = (tid & 1) * 4;
    const int brow = tid >> 5;
    const int bcol = (tid & 31) * 4;

    float acc[8][8];
    #pragma unroll
    for (int i = 0; i < 8; ++i)
        #pragma unroll
        for (int j = 0; j < 8; ++j) acc[i][j] = 0.f;

    for (int k0 = 0; k0 < Kdim; k0 += 8) {
        float4 av = *reinterpret_cast<const float4*>(&A[(size_t)(row0 + arow) * Kdim + k0 + acol]);
        float4 bv = *reinterpret_cast<const float4*>(&W[(size_t)(k0 + brow) * Ndim + col0 + bcol]);
        As[acol + 0][arow] = av.x;
        As[acol + 1][arow] = av.y;
        As[acol + 2][arow] = av.z;
        As[acol + 3][arow] = av.w;
        *reinterpret_cast<float4*>(&Bs[brow][bcol]) = bv;
        __syncthreads();
        #pragma unroll
        for (int k = 0; k < 8; ++k) {
            float4 a0 = *reinterpret_cast<const float4*>(&As[k][ty * 8]);
            float4 a1 = *reinterpret_cast<const float4*>(&As[k][ty * 8 + 4]);
            float4 b0 = *reinterpret_cast<const float4*>(&Bs[k][tx * 8]);
            float4 b1 = *reinterpret_cast<const float4*>(&Bs[k][tx * 8 + 4]);
            float a[8]  = {a0.x, a0.y, a0.z, a0.w, a1.x, a1.y, a1.z, a1.w};
            float bb[8] = {b0.x, b0.y, b0.z, b0.w, b1.x, b1.y, b1.z, b1.w};
            #pragma unroll
            for (int i = 0; i < 8; ++i)
                #pragma unroll
                for (int j = 0; j < 8; ++j)
                    acc[i][j] += a[i] * bb[j];
        }
        __syncthreads();
    }

    const int crow = row0 + ty * 8;
    const int ccol = col0 + tx * 8;
    float bloc[8];
    #pragma unroll
    for (int j = 0; j < 8; ++j) bloc[j] = bias[ccol + j];
    #pragma unroll
    for (int i = 0; i < 8; ++i) {
        float4 o0, o1;
        o0.x = acc[i][0] + bloc[0]; o0.y = acc[i][1] + bloc[1];
        o0.z = acc[i][2] + bloc[2]; o0.w = acc[i][3] + bloc[3];
        o1.x = acc[i][4] + bloc[4]; o1.y = acc[i][5] + bloc[5];
        o1.z = acc[i][6] + bloc[6]; o1.w = acc[i][7] + bloc[7];
        *reinterpret_cast<float4*>(&C[(size_t)(crow + i) * Ndim + ccol])     = o0;
        *reinterpret_cast<float4*>(&C[(size_t)(crow + i) * Ndim + ccol + 4]) = o1;
    }
}

// ---- final GEMM with fused y = O1[l] + O2[l-1] A-operand ----
__global__ __launch_bounds__(256) void sgemm_comb_kernel(
    const float* __restrict__ O1, const float* __restrict__ O2,
    const float* __restrict__ W, const float* __restrict__ bias, float* __restrict__ C,
    int Mdim, int Ndim, int Kdim)
{
    __shared__ float As[8][128];
    __shared__ float Bs[8][132];
    const int tid = threadIdx.x;
    const int row0 = blockIdx.x * 128;
    const int col0 = blockIdx.y * 128;
    const int tx = tid & 15;
    const int ty = tid >> 4;
    const int arow = tid >> 1;
    const int acol = (tid & 1) * 4;
    const int brow = tid >> 5;
    const int bcol = (tid & 31) * 4;

    float acc[8][8];
    #pragma unroll
    for (int i = 0; i < 8; ++i)
        #pragma unroll
        for (int j = 0; j < 8; ++j) acc[i][j] = 0.f;

    const int row = row0 + arow;
    const bool has_prev = (row & (Lsz - 1)) != 0;

    for (int k0 = 0; k0 < Kdim; k0 += 8) {
        float4 av = *reinterpret_cast<const float4*>(&O1[(size_t)row * Kdim + k0 + acol]);
        if (has_prev) {
            float4 o2 = *reinterpret_cast<const float4*>(&O2[(size_t)(row - 1) * Kdim + k0 + acol]);
            av.x += o2.x; av.y += o2.y; av.z += o2.z; av.w += o2.w;
        }
        float4 bv = *reinterpret_cast<const float4*>(&W[(size_t)(k0 + brow) * Ndim + col0 + bcol]);
        As[acol + 0][arow] = av.x;
        As[acol + 1][arow] = av.y;
        As[acol + 2][arow] = av.z;
        As[acol + 3][arow] = av.w;
        *reinterpret_cast<float4*>(&Bs[brow][bcol]) = bv;
        __syncthreads();
        #pragma unroll
        for (int k = 0; k < 8; ++k) {
            float4 a0 = *reinterpret_cast<const float4*>(&As[k][ty * 8]);
            float4 a1 = *reinterpret_cast<const float4*>(&As[k][ty * 8 + 4]);
            float4 b0 = *reinterpret_cast<const float4*>(&Bs[k][tx * 8]);
            float4 b1 = *reinterpret_cast<const float4*>(&Bs[k][tx * 8 + 4]);
            float a[8]  = {a0.x, a0.y, a0.z, a0.w, a1.x, a1.y, a1.z, a1.w};
            float bb[8] = {b0.x, b0.y, b0.z, b0.w, b1.x, b1.y, b1.z, b1.w};
            #pragma unroll
            for (int i = 0; i < 8; ++i)
                #pragma unroll
                for (int j = 0; j < 8; ++j)
                    acc[i][j] += a[i] * bb[j];
        }
        __syncthreads();
    }

    const int crow = row0 + ty * 8;
    const int ccol = col0 + tx * 8;
    float bloc[8];
    #pragma unroll
    for (int j = 0; j < 8; ++j) bloc[j] = bias[ccol + j];
    #pragma unroll
    for (int i = 0; i < 8; ++i) {
        float4 o0, o1;
        o0.x = acc[i][0] + bloc[0]; o0.y = acc[i][1] + bloc[1];
        o0.z = acc[i][2] + bloc[2]; o0.w = acc[i][3] + bloc[3];
        o1.x = acc[i][4] + bloc[4]; o1.y = acc[i][5] + bloc[5];
        o1.z = acc[i][6] + bloc[6]; o1.w = acc[i][7] + bloc[7];
        *reinterpret_cast<float4*>(&C[(size_t)(crow + i) * Ndim + ccol])     = o0;
        *reinterpret_cast<float4*>(&C[(size_t)(crow + i) * Ndim + ccol + 4]) = o1;
    }
}

// ---------------- chunked linear attention ----------------
// Per block: one (b,h,chunk). Computes:
//   dS[d][e]     = sum_j K[j][d] V[j][e]               -> dS buffer
//   O_intra[i][e]= sum_{j<=i} (Q[i].K[j]) V[j][e]      -> overwrites KO (own rows)
__global__ __launch_bounds__(256) void chunk_intra_kernel(
    const float* __restrict__ Qp, float* KO, const float* __restrict__ Vp,
    float* __restrict__ dS)
{
    const int bid = blockIdx.x;
    const int c  = bid & (NC - 1);
    const int bh = bid / NC;
    const int b = bh >> 4, h = bh & 15;
    const int tid = threadIdx.x;

    __shared__ float Qs[64][65], Ks[64][65], Vs[64][65];

    const size_t gbase = ((size_t)b * Lsz + (size_t)c * 64) * Dsz + h * Dh;

    // stage Q,K,V chunk tiles (64x64 each)
    {
        const int col = (tid & 15) * 4;
        const int rb  = tid >> 4;
        #pragma unroll
        for (int k = 0; k < 4; ++k) {
            const int row = rb + k * 16;
            const size_t ga = gbase + (size_t)row * Dsz + col;
            float4 q  = *reinterpret_cast<const float4*>(&Qp[ga]);
            float4 kk = *reinterpret_cast<const float4*>(&KO[ga]);
            float4 v  = *reinterpret_cast<const float4*>(&Vp[ga]);
            Qs[row][col] = q.x; Qs[row][col+1] = q.y; Qs[row][col+2] = q.z; Qs[row][col+3] = q.w;
            Ks[row][col] = kk.x; Ks[row][col+1] = kk.y; Ks[row][col+2] = kk.z; Ks[row][col+3] = kk.w;
            Vs[row][col] = v.x; Vs[row][col+1] = v.y; Vs[row][col+2] = v.z; Vs[row][col+3] = v.w;
        }
    }
    __syncthreads();

    const int r0 = (tid >> 4) * 4;   // output rows (i / d)
    const int c0 = (tid & 15) * 4;   // output cols (j / e)

    // P = Q @ K^T (rows r0.., cols c0..), masked causal (j<=i)
    float p[4][4] = {};
    for (int d = 0; d < 64; ++d) {
        float qa[4], kb[4];
        #pragma unroll
        for (int a = 0; a < 4; ++a) qa[a] = Qs[r0 + a][d];
        #pragma unroll
        for (int bb = 0; bb < 4; ++bb) kb[bb] = Ks[c0 + bb][d];
        #pragma unroll
        for (int a = 0; a < 4; ++a)
            #pragma unroll
            for (int bb = 0; bb < 4; ++bb)
                p[a][bb] += qa[a] * kb[bb];
    }
    #pragma unroll
    for (int a = 0; a < 4; ++a)
        #pragma unroll
        for (int bb = 0; bb < 4; ++bb)
            if (r0 + a < c0 + bb) p[a][bb] = 0.f;

    // dS = K^T @ V (rows=d, cols=e)
    float dt[4][4] = {};
    for (int j = 0; j < 64; ++j) {
        float ka[4], vb[4];
        #pragma unroll
        for (int a = 0; a < 4; ++a) ka[a] = Ks[j][r0 + a];
        #pragma unroll
        for (int bb = 0; bb < 4; ++bb) vb[bb] = Vs[j][c0 + bb];
        #pragma unroll
        for (int a = 0; a < 4; ++a)
            #pragma unroll
            for (int bb = 0; bb < 4; ++bb)
                dt[a][bb] += ka[a] * vb[bb];
    }
    __syncthreads();

    // write P over Qs (Q no longer needed)
    #pragma unroll
    for (int a = 0; a < 4; ++a)
        #pragma unroll
        for (int bb = 0; bb < 4; ++bb)
            Qs[r0 + a][c0 + bb] = p[a][bb];
    __syncthreads();

    // O_intra = P @ V
    float o[4][4] = {};
    for (int j = 0; j < 64; ++j) {
        float pa[4], vb[4];
        #pragma unroll
        for (int a = 0; a < 4; ++a) pa[a] = Qs[r0 + a][j];
        #pragma unroll
        for (int bb = 0; bb < 4; ++bb) vb[bb] = Vs[j][c0 + bb];
        #pragma unroll
        for (int a = 0; a < 4; ++a)
            #pragma unroll
            for (int bb = 0; bb < 4; ++bb)
                o[a][bb] += pa[a] * vb[bb];
    }

    const size_t sbase = ((size_t)bh * NC + c) * 4096;
    #pragma unroll
    for (int a = 0; a < 4; ++a) {
        float4 ov = make_float4(o[a][0], o[a][1], o[a][2], o[a][3]);
        float4 dv = make_float4(dt[a][0], dt[a][1], dt[a][2], dt[a][3]);
        *reinterpret_cast<float4*>(&KO[gbase + (size_t)(r0 + a) * Dsz + c0]) = ov;
        *reinterpret_cast<float4*>(&dS[sbase + (size_t)(r0 + a) * 64 + c0]) = dv;
    }
}

// in-place exclusive prefix over chunks: dS[bh][c] <- sum_{c'<c} dS[bh][c']
__global__ __launch_bounds__(256) void chunk_prefix_kernel(float* dS)
{
    const int bh = blockIdx.x;
    const int t = threadIdx.x;
    float* base = dS + (size_t)bh * NC * 4096;
    float acc[16];
    #pragma unroll
    for (int k = 0; k < 16; ++k) acc[k] = 0.f;
    for (int c = 0; c < NC; ++c) {
        float* p = base + (size_t)c * 4096;
        #pragma unroll
        for (int k = 0; k < 16; ++k) {
            const int idx = t + 256 * k;
            float v = p[idx];
            p[idx] = acc[k];
            acc[k] += v;
        }
    }
}

// O[rows of chunk] += Q_chunk @ S_prev(chunk)
__global__ __launch_bounds__(256) void chunk_inter_kernel(
    const float* __restrict__ Qp, float* O, const float* __restrict__ S)
{
    const int bid = blockIdx.x;
    const int c  = bid & (NC - 1);
    const int bh = bid / NC;
    const int b = bh >> 4, h = bh & 15;
    const int tid = threadIdx.x;

    __shared__ float Qs[64][65], Ss[64][65];

    const size_t gbase = ((size_t)b * Lsz + (size_t)c * 64) * Dsz + h * Dh;
    const size_t sbase = ((size_t)bh * NC + c) * 4096;

    {
        const int col = (tid & 15) * 4;
        const int rb  = tid >> 4;
        #pragma unroll
        for (int k = 0; k < 4; ++k) {
            const int row = rb + k * 16;
            float4 q = *reinterpret_cast<const float4*>(&Qp[gbase + (size_t)row * Dsz + col]);
            float4 s = *reinterpret_cast<const float4*>(&S[sbase + (size_t)row * 64 + col]);
            Qs[row][col] = q.x; Qs[row][col+1] = q.y; Qs[row][col+2] = q.z; Qs[row][col+3] = q.w;
            Ss[row][col] = s.x; Ss[row][col+1] = s.y; Ss[row][col+2] = s.z; Ss[row][col+3] = s.w;
        }
    }
    __syncthreads();

    const int r0 = (tid >> 4) * 4;
    const int c0 = (tid & 15) * 4;

    float o[4][4] = {};
    for (int d = 0; d < 64; ++d) {
        float qa[4], sb[4];
        #pragma unroll
        for (int a = 0; a < 4; ++a) qa[a] = Qs[r0 + a][d];
        #pragma unroll
        for (int bb = 0; bb < 4; ++bb) sb[bb] = Ss[d][c0 + bb];
        #pragma unroll
        for (int a = 0; a < 4; ++a)
            #pragma unroll
            for (int bb = 0; bb < 4; ++bb)
                o[a][bb] += qa[a] * sb[bb];
    }

    #pragma unroll
    for (int a = 0; a < 4; ++a) {
        float* dst = &O[gbase + (size_t)(r0 + a) * Dsz + c0];
        float4 cur = *reinterpret_cast<const float4*>(dst);
        cur.x += o[a][0]; cur.y += o[a][1]; cur.z += o[a][2]; cur.w += o[a][3];
        *reinterpret_cast<float4*>(dst) = cur;
    }
}

// elementwise: k2 = sigmoid(z*0.02/32) over Z; q2 = f(Q) over Q; E = x[l+1]-O1[l] -> E buffer
__global__ __launch_bounds__(256) void ew_kernel(
    const float* __restrict__ x, const float* __restrict__ O1,
    float* Z, float* Q, float* E)
{
    const int i4 = blockIdx.x * 256 + threadIdx.x;   // 524288 float4s
    const size_t fi = (size_t)i4 * 4;
    const int l = (int)((fi >> 10) & (Lsz - 1));

    float4 z = *reinterpret_cast<const float4*>(&Z[fi]);
    z.x = 1.f / (1.f + __expf(-z.x * 0.000625f));
    z.y = 1.f / (1.f + __expf(-z.y * 0.000625f));
    z.z = 1.f / (1.f + __expf(-z.z * 0.000625f));
    z.w = 1.f / (1.f + __expf(-z.w * 0.000625f));
    *reinterpret_cast<float4*>(&Z[fi]) = z;

    float4 q = *reinterpret_cast<const float4*>(&Q[fi]);
    q.x = (q.x >= 0.f ? 0.02f * q.x : q.x) * 0.125f;
    q.y = (q.y >= 0.f ? 0.02f * q.y : q.y) * 0.125f;
    q.z = (q.z >= 0.f ? 0.02f * q.z : q.z) * 0.125f;
    q.w = (q.w >= 0.f ? 0.02f * q.w : q.w) * 0.125f;
    *reinterpret_cast<float4*>(&Q[fi]) = q;

    float4 e;
    if (l == Lsz - 1) {
        e = make_float4(0.f, 0.f, 0.f, 0.f);
    } else {
        float4 xv = *reinterpret_cast<const float4*>(&x[fi + Dsz]);
        float4 ov = *reinterpret_cast<const float4*>(&O1[fi]);
        e = make_float4(xv.x - ov.x, xv.y - ov.y, xv.z - ov.z, xv.w - ov.w);
    }
    *reinterpret_cast<float4*>(&E[fi]) = e;
}

extern "C" void kernel_launch(void* const* d_in, const int* in_sizes, int n_in,
                              void* d_out, int out_size, void* d_ws, size_t ws_size,
                              hipStream_t stream) {
    const float* x   = (const float*)d_in[0];
    const float* Wq  = (const float*)d_in[1];
    const float* bq  = (const float*)d_in[2];
    const float* Wk1 = (const float*)d_in[3];
    const float* bk1 = (const float*)d_in[4];
    const float* Wv  = (const float*)d_in[5];
    const float* bv  = (const float*)d_in[6];
    const float* Wk2 = (const float*)d_in[7];
    const float* bk2 = (const float*)d_in[8];
    const float* Wp  = (const float*)d_in[9];
    const float* bp  = (const float*)d_in[10];
    float* out = (float*)d_out;
    float* ws  = (float*)d_ws;

    const size_t mat = (size_t)Mtot * Dsz;   // 2M floats
    float* Qb  = ws;            // Q -> q2
    float* Kb  = ws + mat;      // K -> O_intra1 -> O1
    float* Vb  = ws + 2 * mat;  // V -> E
    float* Zb  = ws + 3 * mat;  // Z -> k2 -> O_intra2 -> O2
    float* dSS = ws + 4 * mat;  // 32*16*4096 = 2M floats

    dim3 grid(Mtot / 128, Dsz / 128);
    dim3 block(256);
    sgemm_kernel<<<grid, block, 0, stream>>>(x, Wq,  bq,  Qb, Mtot, Dsz, Dsz);
    sgemm_kernel<<<grid, block, 0, stream>>>(x, Wk1, bk1, Kb, Mtot, Dsz, Dsz);
    sgemm_kernel<<<grid, block, 0, stream>>>(x, Wv,  bv,  Vb, Mtot, Dsz, Dsz);
    sgemm_kernel<<<grid, block, 0, stream>>>(x, Wk2, bk2, Zb, Mtot, Dsz, Dsz);

    const int nchunkblocks = Bsz * Hsz * NC;   // 512
    // branch 1
    chunk_intra_kernel<<<nchunkblocks, block, 0, stream>>>(Qb, Kb, Vb, dSS);
    chunk_prefix_kernel<<<Bsz * Hsz, block, 0, stream>>>(dSS);
    chunk_inter_kernel<<<nchunkblocks, block, 0, stream>>>(Qb, Kb, dSS);   // Kb = O1
    // elementwise: E, k2, q2
    ew_kernel<<<(Mtot * Dsz / 4) / 256, block, 0, stream>>>(x, Kb, Zb, Qb, Vb);
    // branch 2 (keys=k2 in Zb, values=E in Vb, queries=q2 in Qb)
    chunk_intra_kernel<<<nchunkblocks, block, 0, stream>>>(Qb, Zb, Vb, dSS);
    chunk_prefix_kernel<<<Bsz * Hsz, block, 0, stream>>>(dSS);
    chunk_inter_kernel<<<nchunkblocks, block, 0, stream>>>(Qb, Zb, dSS);   // Zb = O2
    // out = (O1 + shift(O2)) @ Wp + bp
    sgemm_comb_kernel<<<grid, block, 0, stream>>>(Kb, Zb, Wp, bp, out, Mtot, Dsz, Dsz);
}

// Round 3
// 231.677 us; speedup vs baseline: 10.3988x; 3.8378x over previous
//
#include <hip/hip_runtime.h>
#include <hip/hip_bf16.h>
#include <math.h>

#define Bsz 2
#define Lsz 1024
#define Dsz 1024
#define Hsz 16
#define Dh 64
#define Mtot (Bsz*Lsz)   // 2048
#define NC (Lsz/64)      // 16 chunks per (b,h)

typedef __bf16 bf16_t;
typedef bf16_t bf16x8 __attribute__((ext_vector_type(8)));
typedef bf16_t bf16x4 __attribute__((ext_vector_type(4)));
typedef float f32x4v __attribute__((ext_vector_type(4)));

__device__ __forceinline__ void gload16(const void* g, void* l) {
    __builtin_amdgcn_global_load_lds(
        (const __attribute__((address_space(1))) unsigned int*)g,
        (__attribute__((address_space(3))) unsigned int*)l, 16, 0, 0);
}

// ---------------- bf16 MFMA GEMM: C(f32) = A(bf16) @ Bt(bf16)^T + bias ----------------
// A: M x K row-major bf16. Bt: N x K row-major bf16 (i.e. W transposed).
// Tile 128x128, BK=32, 256 threads = 4 waves (2x2), each wave 64x64 via 4x4
// fragments of mfma_f32_16x16x32_bf16. LDS staged via global_load_lds width=16
// with XOR chunk swizzle (kblk ^ row[1:0] ^ row[3:2]) pre-applied on the
// global source (linear LDS dest) and re-applied on ds_read (rule 21).
__global__ __launch_bounds__(256) void bgemm_kernel(
    const bf16_t* __restrict__ A, const bf16_t* __restrict__ Bt,
    const float* __restrict__ bias, float* __restrict__ C,
    int Ndim, int Kdim)
{
    __shared__ __align__(16) bf16_t As[128 * 32];
    __shared__ __align__(16) bf16_t Bs[128 * 32];
    const int tid  = threadIdx.x;
    const int lane = tid & 63;
    const int wid  = tid >> 6;
    const int row0 = blockIdx.x * 128;
    const int col0 = blockIdx.y * 128;
    const int wr = (wid >> 1) * 64;
    const int wc = (wid & 1) * 64;

    // staging: thread t stages 16B chunks t and t+256 per tile.
    // chunk c -> (row=c>>2, col16=c&3); source col pre-swizzled.
    const int srow = tid >> 2;          // 0..63 (and +64 for second chunk)
    const int scol = tid & 3;
    const int ssw  = (srow & 3) ^ ((srow >> 2) & 3);   // same for srow+64
    const int scol_sw = scol ^ ssw;
    const bf16_t* gA0 = A  + (size_t)(row0 + srow)      * Kdim + scol_sw * 8;
    const bf16_t* gA1 = A  + (size_t)(row0 + srow + 64) * Kdim + scol_sw * 8;
    const bf16_t* gB0 = Bt + (size_t)(col0 + srow)      * Kdim + scol_sw * 8;
    const bf16_t* gB1 = Bt + (size_t)(col0 + srow + 64) * Kdim + scol_sw * 8;
    bf16_t* lA0 = As + tid * 8;
    bf16_t* lA1 = As + (tid + 256) * 8;
    bf16_t* lB0 = Bs + tid * 8;
    bf16_t* lB1 = Bs + (tid + 256) * 8;

    // fragment read offsets (elements); swizzle constant per lane
    const int laneRow = lane & 15;
    const int kblk = lane >> 4;
    const int swz = (kblk ^ (laneRow & 3) ^ ((laneRow >> 2) & 3)) & 3;
    const int aoff = (wr + laneRow) * 32 + swz * 8;
    const int boff = (wc + laneRow) * 32 + swz * 8;

    f32x4v acc[4][4];
    #pragma unroll
    for (int i = 0; i < 4; ++i)
        #pragma unroll
        for (int j = 0; j < 4; ++j)
            acc[i][j] = (f32x4v){0.f, 0.f, 0.f, 0.f};

    for (int k0 = 0; k0 < Kdim; k0 += 32) {
        __syncthreads();                 // previous compute done before overwrite
        gload16(gA0, lA0);
        gload16(gA1, lA1);
        gload16(gB0, lB0);
        gload16(gB1, lB1);
        gA0 += 32; gA1 += 32; gB0 += 32; gB1 += 32;
        __syncthreads();                 // drains vmcnt -> tiles ready

        bf16x8 af[4], bfr[4];
        #pragma unroll
        for (int f = 0; f < 4; ++f) {
            af[f]  = *reinterpret_cast<const bf16x8*>(As + aoff + f * 512);
            bfr[f] = *reinterpret_cast<const bf16x8*>(Bs + boff + f * 512);
        }
        #pragma unroll
        for (int i = 0; i < 4; ++i)
            #pragma unroll
            for (int j = 0; j < 4; ++j)
                acc[i][j] = __builtin_amdgcn_mfma_f32_16x16x32_bf16(af[i], bfr[j], acc[i][j], 0, 0, 0);
    }

    // epilogue: C/D layout col=lane&15, row=(lane>>4)*4+e
    const int crowb = row0 + wr + (lane >> 4) * 4;
    const int ccolb = col0 + wc + laneRow;
    float bv[4];
    #pragma unroll
    for (int j = 0; j < 4; ++j) bv[j] = bias[ccolb + j * 16];
    #pragma unroll
    for (int i = 0; i < 4; ++i)
        #pragma unroll
        for (int j = 0; j < 4; ++j)
            #pragma unroll
            for (int e = 0; e < 4; ++e)
                C[(size_t)(crowb + i * 16 + e) * Ndim + ccolb + j * 16] = acc[i][j][e] + bv[j];
}

// ---------------- f32 -> bf16 cast ----------------
__global__ __launch_bounds__(256) void cast_kernel(const float* __restrict__ in, bf16_t* __restrict__ ob)
{
    const size_t fi = ((size_t)blockIdx.x * 256 + threadIdx.x) * 4;
    float4 v = *reinterpret_cast<const float4*>(&in[fi]);
    bf16x4 o;
    o[0] = (bf16_t)v.x; o[1] = (bf16_t)v.y; o[2] = (bf16_t)v.z; o[3] = (bf16_t)v.w;
    *reinterpret_cast<bf16x4*>(&ob[fi]) = o;
}

// ---------------- W (KxN f32) -> Wt (NxK bf16), 64x64 LDS tiles ----------------
__global__ __launch_bounds__(256) void transpose_cast_kernel(
    const float* __restrict__ W0, const float* __restrict__ W1,
    const float* __restrict__ W2, const float* __restrict__ W3,
    const float* __restrict__ W4,
    bf16_t* __restrict__ T0, bf16_t* __restrict__ T1,
    bf16_t* __restrict__ T2, bf16_t* __restrict__ T3, bf16_t* __restrict__ T4)
{
    const float* W; bf16_t* T;
    const int z = blockIdx.z;
    if      (z == 0) { W = W0; T = T0; }
    else if (z == 1) { W = W1; T = T1; }
    else if (z == 2) { W = W2; T = T2; }
    else if (z == 3) { W = W3; T = T3; }
    else             { W = W4; T = T4; }

    __shared__ float Ls[64][65];
    const int k0 = blockIdx.x * 64;
    const int n0 = blockIdx.y * 64;
    const int tid = threadIdx.x;
    const int r  = tid >> 4;
    const int c4 = (tid & 15) * 4;
    #pragma unroll
    for (int i = 0; i < 4; ++i) {
        float4 v = *reinterpret_cast<const float4*>(&W[(size_t)(k0 + r + i * 16) * Dsz + n0 + c4]);
        Ls[r + i * 16][c4 + 0] = v.x;
        Ls[r + i * 16][c4 + 1] = v.y;
        Ls[r + i * 16][c4 + 2] = v.z;
        Ls[r + i * 16][c4 + 3] = v.w;
    }
    __syncthreads();
    #pragma unroll
    for (int i = 0; i < 4; ++i) {
        const int n = r + i * 16;
        bf16x4 o;
        o[0] = (bf16_t)Ls[c4 + 0][n];
        o[1] = (bf16_t)Ls[c4 + 1][n];
        o[2] = (bf16_t)Ls[c4 + 2][n];
        o[3] = (bf16_t)Ls[c4 + 3][n];
        *reinterpret_cast<bf16x4*>(&T[(size_t)(n0 + n) * Dsz + k0 + c4]) = o;
    }
}

// ---------------- chunked linear attention (fp32, unchanged) ----------------
__global__ __launch_bounds__(256) void chunk_intra_kernel(
    const float* __restrict__ Qp, float* KO, const float* __restrict__ Vp,
    float* __restrict__ dS)
{
    const int bid = blockIdx.x;
    const int c  = bid & (NC - 1);
    const int bh = bid / NC;
    const int b = bh >> 4, h = bh & 15;
    const int tid = threadIdx.x;

    __shared__ float Qs[64][65], Ks[64][65], Vs[64][65];

    const size_t gbase = ((size_t)b * Lsz + (size_t)c * 64) * Dsz + h * Dh;

    {
        const int col = (tid & 15) * 4;
        const int rb  = tid >> 4;
        #pragma unroll
        for (int k = 0; k < 4; ++k) {
            const int row = rb + k * 16;
            const size_t ga = gbase + (size_t)row * Dsz + col;
            float4 q  = *reinterpret_cast<const float4*>(&Qp[ga]);
            float4 kk = *reinterpret_cast<const float4*>(&KO[ga]);
            float4 v  = *reinterpret_cast<const float4*>(&Vp[ga]);
            Qs[row][col] = q.x; Qs[row][col+1] = q.y; Qs[row][col+2] = q.z; Qs[row][col+3] = q.w;
            Ks[row][col] = kk.x; Ks[row][col+1] = kk.y; Ks[row][col+2] = kk.z; Ks[row][col+3] = kk.w;
            Vs[row][col] = v.x; Vs[row][col+1] = v.y; Vs[row][col+2] = v.z; Vs[row][col+3] = v.w;
        }
    }
    __syncthreads();

    const int r0 = (tid >> 4) * 4;
    const int c0 = (tid & 15) * 4;

    float p[4][4] = {};
    for (int d = 0; d < 64; ++d) {
        float qa[4], kb[4];
        #pragma unroll
        for (int a = 0; a < 4; ++a) qa[a] = Qs[r0 + a][d];
        #pragma unroll
        for (int bb = 0; bb < 4; ++bb) kb[bb] = Ks[c0 + bb][d];
        #pragma unroll
        for (int a = 0; a < 4; ++a)
            #pragma unroll
            for (int bb = 0; bb < 4; ++bb)
                p[a][bb] += qa[a] * kb[bb];
    }
    #pragma unroll
    for (int a = 0; a < 4; ++a)
        #pragma unroll
        for (int bb = 0; bb < 4; ++bb)
            if (r0 + a < c0 + bb) p[a][bb] = 0.f;

    float dt[4][4] = {};
    for (int j = 0; j < 64; ++j) {
        float ka[4], vb[4];
        #pragma unroll
        for (int a = 0; a < 4; ++a) ka[a] = Ks[j][r0 + a];
        #pragma unroll
        for (int bb = 0; bb < 4; ++bb) vb[bb] = Vs[j][c0 + bb];
        #pragma unroll
        for (int a = 0; a < 4; ++a)
            #pragma unroll
            for (int bb = 0; bb < 4; ++bb)
                dt[a][bb] += ka[a] * vb[bb];
    }
    __syncthreads();

    #pragma unroll
    for (int a = 0; a < 4; ++a)
        #pragma unroll
        for (int bb = 0; bb < 4; ++bb)
            Qs[r0 + a][c0 + bb] = p[a][bb];
    __syncthreads();

    float o[4][4] = {};
    for (int j = 0; j < 64; ++j) {
        float pa[4], vb[4];
        #pragma unroll
        for (int a = 0; a < 4; ++a) pa[a] = Qs[r0 + a][j];
        #pragma unroll
        for (int bb = 0; bb < 4; ++bb) vb[bb] = Vs[j][c0 + bb];
        #pragma unroll
        for (int a = 0; a < 4; ++a)
            #pragma unroll
            for (int bb = 0; bb < 4; ++bb)
                o[a][bb] += pa[a] * vb[bb];
    }

    const size_t sbase = ((size_t)bh * NC + c) * 4096;
    #pragma unroll
    for (int a = 0; a < 4; ++a) {
        float4 ov = make_float4(o[a][0], o[a][1], o[a][2], o[a][3]);
        float4 dv = make_float4(dt[a][0], dt[a][1], dt[a][2], dt[a][3]);
        *reinterpret_cast<float4*>(&KO[gbase + (size_t)(r0 + a) * Dsz + c0]) = ov;
        *reinterpret_cast<float4*>(&dS[sbase + (size_t)(r0 + a) * 64 + c0]) = dv;
    }
}

__global__ __launch_bounds__(256) void chunk_prefix_kernel(float* dS)
{
    const int bh = blockIdx.x;
    const int t = threadIdx.x;
    float* base = dS + (size_t)bh * NC * 4096;
    float acc[16];
    #pragma unroll
    for (int k = 0; k < 16; ++k) acc[k] = 0.f;
    for (int c = 0; c < NC; ++c) {
        float* p = base + (size_t)c * 4096;
        #pragma unroll
        for (int k = 0; k < 16; ++k) {
            const int idx = t + 256 * k;
            float v = p[idx];
            p[idx] = acc[k];
            acc[k] += v;
        }
    }
}

__global__ __launch_bounds__(256) void chunk_inter_kernel(
    const float* __restrict__ Qp, float* O, const float* __restrict__ S)
{
    const int bid = blockIdx.x;
    const int c  = bid & (NC - 1);
    const int bh = bid / NC;
    const int b = bh >> 4, h = bh & 15;
    const int tid = threadIdx.x;

    __shared__ float Qs[64][65], Ss[64][65];

    const size_t gbase = ((size_t)b * Lsz + (size_t)c * 64) * Dsz + h * Dh;
    const size_t sbase = ((size_t)bh * NC + c) * 4096;

    {
        const int col = (tid & 15) * 4;
        const int rb  = tid >> 4;
        #pragma unroll
        for (int k = 0; k < 4; ++k) {
            const int row = rb + k * 16;
            float4 q = *reinterpret_cast<const float4*>(&Qp[gbase + (size_t)row * Dsz + col]);
            float4 s = *reinterpret_cast<const float4*>(&S[sbase + (size_t)row * 64 + col]);
            Qs[row][col] = q.x; Qs[row][col+1] = q.y; Qs[row][col+2] = q.z; Qs[row][col+3] = q.w;
            Ss[row][col] = s.x; Ss[row][col+1] = s.y; Ss[row][col+2] = s.z; Ss[row][col+3] = s.w;
        }
    }
    __syncthreads();

    const int r0 = (tid >> 4) * 4;
    const int c0 = (tid & 15) * 4;

    float o[4][4] = {};
    for (int d = 0; d < 64; ++d) {
        float qa[4], sb[4];
        #pragma unroll
        for (int a = 0; a < 4; ++a) qa[a] = Qs[r0 + a][d];
        #pragma unroll
        for (int bb = 0; bb < 4; ++bb) sb[bb] = Ss[d][c0 + bb];
        #pragma unroll
        for (int a = 0; a < 4; ++a)
            #pragma unroll
            for (int bb = 0; bb < 4; ++bb)
                o[a][bb] += qa[a] * sb[bb];
    }

    #pragma unroll
    for (int a = 0; a < 4; ++a) {
        float* dst = &O[gbase + (size_t)(r0 + a) * Dsz + c0];
        float4 cur = *reinterpret_cast<const float4*>(dst);
        cur.x += o[a][0]; cur.y += o[a][1]; cur.z += o[a][2]; cur.w += o[a][3];
        *reinterpret_cast<float4*>(dst) = cur;
    }
}

// elementwise: k2 over Z, q2 over Q, E = x[l+1]-O1[l] -> E
__global__ __launch_bounds__(256) void ew_kernel(
    const float* __restrict__ x, const float* __restrict__ O1,
    float* Z, float* Q, float* E)
{
    const int i4 = blockIdx.x * 256 + threadIdx.x;
    const size_t fi = (size_t)i4 * 4;
    const int l = (int)((fi >> 10) & (Lsz - 1));

    float4 z = *reinterpret_cast<const float4*>(&Z[fi]);
    z.x = 1.f / (1.f + __expf(-z.x * 0.000625f));
    z.y = 1.f / (1.f + __expf(-z.y * 0.000625f));
    z.z = 1.f / (1.f + __expf(-z.z * 0.000625f));
    z.w = 1.f / (1.f + __expf(-z.w * 0.000625f));
    *reinterpret_cast<float4*>(&Z[fi]) = z;

    float4 q = *reinterpret_cast<const float4*>(&Q[fi]);
    q.x = (q.x >= 0.f ? 0.02f * q.x : q.x) * 0.125f;
    q.y = (q.y >= 0.f ? 0.02f * q.y : q.y) * 0.125f;
    q.z = (q.z >= 0.f ? 0.02f * q.z : q.z) * 0.125f;
    q.w = (q.w >= 0.f ? 0.02f * q.w : q.w) * 0.125f;
    *reinterpret_cast<float4*>(&Q[fi]) = q;

    float4 e;
    if (l == Lsz - 1) {
        e = make_float4(0.f, 0.f, 0.f, 0.f);
    } else {
        float4 xv = *reinterpret_cast<const float4*>(&x[fi + Dsz]);
        float4 ov = *reinterpret_cast<const float4*>(&O1[fi]);
        e = make_float4(xv.x - ov.x, xv.y - ov.y, xv.z - ov.z, xv.w - ov.w);
    }
    *reinterpret_cast<float4*>(&E[fi]) = e;
}

// yb = bf16(O1[l] + (l>0 ? O2[l-1] : 0))
__global__ __launch_bounds__(256) void combine_kernel(
    const float* __restrict__ O1, const float* __restrict__ O2, bf16_t* __restrict__ yb)
{
    const size_t fi = ((size_t)blockIdx.x * 256 + threadIdx.x) * 4;
    const int l = (int)((fi >> 10) & (Lsz - 1));
    float4 a = *reinterpret_cast<const float4*>(&O1[fi]);
    if (l > 0) {
        float4 b2 = *reinterpret_cast<const float4*>(&O2[fi - Dsz]);
        a.x += b2.x; a.y += b2.y; a.z += b2.z; a.w += b2.w;
    }
    bf16x4 o;
    o[0] = (bf16_t)a.x; o[1] = (bf16_t)a.y; o[2] = (bf16_t)a.z; o[3] = (bf16_t)a.w;
    *reinterpret_cast<bf16x4*>(&yb[fi]) = o;
}

extern "C" void kernel_launch(void* const* d_in, const int* in_sizes, int n_in,
                              void* d_out, int out_size, void* d_ws, size_t ws_size,
                              hipStream_t stream) {
    const float* x   = (const float*)d_in[0];
    const float* Wq  = (const float*)d_in[1];
    const float* bq  = (const float*)d_in[2];
    const float* Wk1 = (const float*)d_in[3];
    const float* bk1 = (const float*)d_in[4];
    const float* Wv  = (const float*)d_in[5];
    const float* bv  = (const float*)d_in[6];
    const float* Wk2 = (const float*)d_in[7];
    const float* bk2 = (const float*)d_in[8];
    const float* Wp  = (const float*)d_in[9];
    const float* bp  = (const float*)d_in[10];
    float* out = (float*)d_out;
    float* ws  = (float*)d_ws;

    const size_t mat = (size_t)Mtot * Dsz;   // 2M elements
    float* Qb  = ws;             // f32 Q -> q2
    float* Kb  = ws + mat;       // f32 K -> O1
    float* Vb  = ws + 2 * mat;   // f32 V -> E
    float* dSS = ws + 3 * mat;   // f32 chunk states (2M); later reused for yb
    bf16_t* xb = (bf16_t*)(ws + 4 * mat);            // bf16 x (2M bf16 = 1M f32 slots)
    bf16_t* Wt = (bf16_t*)(ws + 4 * mat + mat / 2);  // 5 x (1M bf16)
    bf16_t* T0 = Wt;
    bf16_t* T1 = Wt + 1048576;
    bf16_t* T2 = Wt + 2 * 1048576;
    bf16_t* T3 = Wt + 3 * 1048576;
    bf16_t* T4 = Wt + 4 * 1048576;
    float* Zb = out;             // use d_out as f32 scratch for Z -> k2 -> O2
    bf16_t* yb = (bf16_t*)dSS;   // combine output (dSS dead by then)

    dim3 block(256);
    dim3 ggrid(Mtot / 128, Dsz / 128);   // 16 x 8

    cast_kernel<<<dim3(2048), block, 0, stream>>>(x, xb);
    transpose_cast_kernel<<<dim3(16, 16, 5), block, 0, stream>>>(
        Wq, Wk1, Wv, Wk2, Wp, T0, T1, T2, T3, T4);

    bgemm_kernel<<<ggrid, block, 0, stream>>>(xb, T0, bq,  Qb, Dsz, Dsz);
    bgemm_kernel<<<ggrid, block, 0, stream>>>(xb, T1, bk1, Kb, Dsz, Dsz);
    bgemm_kernel<<<ggrid, block, 0, stream>>>(xb, T2, bv,  Vb, Dsz, Dsz);
    bgemm_kernel<<<ggrid, block, 0, stream>>>(xb, T3, bk2, Zb, Dsz, Dsz);

    const int nchunkblocks = Bsz * Hsz * NC;   // 512
    chunk_intra_kernel<<<dim3(nchunkblocks), block, 0, stream>>>(Qb, Kb, Vb, dSS);
    chunk_prefix_kernel<<<dim3(Bsz * Hsz), block, 0, stream>>>(dSS);
    chunk_inter_kernel<<<dim3(nchunkblocks), block, 0, stream>>>(Qb, Kb, dSS);   // Kb = O1
    ew_kernel<<<dim3(2048), block, 0, stream>>>(x, Kb, Zb, Qb, Vb);
    chunk_intra_kernel<<<dim3(nchunkblocks), block, 0, stream>>>(Qb, Zb, Vb, dSS);
    chunk_prefix_kernel<<<dim3(Bsz * Hsz), block, 0, stream>>>(dSS);
    chunk_inter_kernel<<<dim3(nchunkblocks), block, 0, stream>>>(Qb, Zb, dSS);   // Zb = O2

    combine_kernel<<<dim3(2048), block, 0, stream>>>(Kb, Zb, yb);
    bgemm_kernel<<<ggrid, block, 0, stream>>>(yb, T4, bp, out, Dsz, Dsz);
}

// Round 4
// 154.716 us; speedup vs baseline: 15.5714x; 1.4974x over previous
//
#include <hip/hip_runtime.h>
#include <hip/hip_bf16.h>
#include <math.h>

#define Bsz 2
#define Lsz 1024
#define Dsz 1024
#define Hsz 16
#define Dh 64
#define Mtot (Bsz*Lsz)   // 2048
#define NC (Lsz/64)      // 16 chunks per (b,h)

typedef __bf16 bf16_t;
typedef bf16_t bf16x8 __attribute__((ext_vector_type(8)));
typedef bf16_t bf16x4 __attribute__((ext_vector_type(4)));
typedef float f32x4v __attribute__((ext_vector_type(4)));

__device__ __forceinline__ void gload16(const void* g, void* l) {
    __builtin_amdgcn_global_load_lds(
        (const __attribute__((address_space(1))) unsigned int*)g,
        (__attribute__((address_space(3))) unsigned int*)l, 16, 0, 0);
}

// ---------------- bf16 MFMA GEMM, 4-way fused N, 2-phase double-buffer ----------------
// A: M x 1024 bf16 row-major. Bt: Ntot x 1024 bf16 row-major (concatenated W^T).
// gridDim.y * 128 = Ntot. Output column block col0g selects projection p = col0g>>10,
// writes C[p] (M x 1024 f32) at local col (col0g & 1023) with bias[p].
// Tile 128x128, BK=32, 4 waves (2x2), mfma_f32_16x16x32_bf16, 4x4 frags/wave.
// LDS double-buffered; next tile's global_load_lds issued before current compute.
__global__ __launch_bounds__(256) void bgemm4_kernel(
    const bf16_t* __restrict__ A, const bf16_t* __restrict__ Bt,
    float* C0, float* C1, float* C2, float* C3,
    const float* b0, const float* b1, const float* b2, const float* b3)
{
    __shared__ __align__(16) bf16_t As[2][4096];
    __shared__ __align__(16) bf16_t Bs[2][4096];
    const int tid  = threadIdx.x;
    const int lane = tid & 63;
    const int wid  = tid >> 6;
    const int row0  = blockIdx.x * 128;
    const int col0g = blockIdx.y * 128;
    const int p    = col0g >> 10;
    const int col0 = col0g & 1023;
    float* C = (p == 0) ? C0 : (p == 1) ? C1 : (p == 2) ? C2 : C3;
    const float* bias = (p == 0) ? b0 : (p == 1) ? b1 : (p == 2) ? b2 : b3;
    const int wr = (wid >> 1) * 64;
    const int wc = (wid & 1) * 64;

    // staging: thread t stages 16B chunks t and t+256 per tile (row=c>>2, col16=c&3),
    // source column pre-swizzled (rule 21: linear LDS dest + inverse-swizzled source).
    const int srow = tid >> 2;
    const int scol = tid & 3;
    const int ssw  = (srow & 3) ^ ((srow >> 2) & 3);
    const int scol_sw = scol ^ ssw;
    const bf16_t* gA0 = A  + (size_t)(row0 + srow)       * 1024 + scol_sw * 8;
    const bf16_t* gA1 = A  + (size_t)(row0 + srow + 64)  * 1024 + scol_sw * 8;
    const bf16_t* gB0 = Bt + (size_t)(col0g + srow)      * 1024 + scol_sw * 8;
    const bf16_t* gB1 = Bt + (size_t)(col0g + srow + 64) * 1024 + scol_sw * 8;

    // fragment read offsets; same swizzle applied on read
    const int laneRow = lane & 15;
    const int kblk = lane >> 4;
    const int swz = (kblk ^ (laneRow & 3) ^ ((laneRow >> 2) & 3)) & 3;
    const int aoff = (wr + laneRow) * 32 + swz * 8;
    const int boff = (wc + laneRow) * 32 + swz * 8;

    f32x4v acc[4][4];
    #pragma unroll
    for (int i = 0; i < 4; ++i)
        #pragma unroll
        for (int j = 0; j < 4; ++j)
            acc[i][j] = (f32x4v){0.f, 0.f, 0.f, 0.f};

    // prologue: stage k=0 into buf 0
    gload16(gA0, &As[0][tid * 8]);
    gload16(gA1, &As[0][(tid + 256) * 8]);
    gload16(gB0, &Bs[0][tid * 8]);
    gload16(gB1, &Bs[0][(tid + 256) * 8]);
    gA0 += 32; gA1 += 32; gB0 += 32; gB1 += 32;
    asm volatile("s_waitcnt vmcnt(0)" ::: "memory");
    __builtin_amdgcn_s_barrier();

    int cur = 0;
    for (int k0 = 0; k0 < 1024; k0 += 32) {
        if (k0 + 32 < 1024) {
            const int nxt = cur ^ 1;
            gload16(gA0, &As[nxt][tid * 8]);
            gload16(gA1, &As[nxt][(tid + 256) * 8]);
            gload16(gB0, &Bs[nxt][tid * 8]);
            gload16(gB1, &Bs[nxt][(tid + 256) * 8]);
            gA0 += 32; gA1 += 32; gB0 += 32; gB1 += 32;
        }
        bf16x8 af[4], bfr[4];
        #pragma unroll
        for (int f = 0; f < 4; ++f) {
            af[f]  = *reinterpret_cast<const bf16x8*>(&As[cur][aoff + f * 512]);
            bfr[f] = *reinterpret_cast<const bf16x8*>(&Bs[cur][boff + f * 512]);
        }
        #pragma unroll
        for (int i = 0; i < 4; ++i)
            #pragma unroll
            for (int j = 0; j < 4; ++j)
                acc[i][j] = __builtin_amdgcn_mfma_f32_16x16x32_bf16(af[i], bfr[j], acc[i][j], 0, 0, 0);
        asm volatile("s_waitcnt vmcnt(0)" ::: "memory");
        __builtin_amdgcn_s_barrier();
        cur ^= 1;
    }

    // epilogue: C/D layout col=lane&15, row=(lane>>4)*4+e
    const int crowb = row0 + wr + kblk * 4;
    const int ccolb = col0 + wc + laneRow;
    float bv[4];
    #pragma unroll
    for (int j = 0; j < 4; ++j) bv[j] = bias[ccolb + j * 16];
    #pragma unroll
    for (int i = 0; i < 4; ++i)
        #pragma unroll
        for (int j = 0; j < 4; ++j)
            #pragma unroll
            for (int e = 0; e < 4; ++e)
                C[(size_t)(crowb + i * 16 + e) * 1024 + ccolb + j * 16] = acc[i][j][e] + bv[j];
}

// ---------------- f32 -> bf16 cast ----------------
__global__ __launch_bounds__(256) void cast_kernel(const float* __restrict__ in, bf16_t* __restrict__ ob)
{
    const size_t fi = ((size_t)blockIdx.x * 256 + threadIdx.x) * 4;
    float4 v = *reinterpret_cast<const float4*>(&in[fi]);
    bf16x4 o;
    o[0] = (bf16_t)v.x; o[1] = (bf16_t)v.y; o[2] = (bf16_t)v.z; o[3] = (bf16_t)v.w;
    *reinterpret_cast<bf16x4*>(&ob[fi]) = o;
}

// ---------------- W (KxN f32) -> Wt (NxK bf16), 64x64 LDS tiles ----------------
__global__ __launch_bounds__(256) void transpose_cast_kernel(
    const float* __restrict__ W0, const float* __restrict__ W1,
    const float* __restrict__ W2, const float* __restrict__ W3,
    const float* __restrict__ W4,
    bf16_t* __restrict__ T0, bf16_t* __restrict__ T1,
    bf16_t* __restrict__ T2, bf16_t* __restrict__ T3, bf16_t* __restrict__ T4)
{
    const float* W; bf16_t* T;
    const int z = blockIdx.z;
    if      (z == 0) { W = W0; T = T0; }
    else if (z == 1) { W = W1; T = T1; }
    else if (z == 2) { W = W2; T = T2; }
    else if (z == 3) { W = W3; T = T3; }
    else             { W = W4; T = T4; }

    __shared__ float Ls[64][65];
    const int k0 = blockIdx.x * 64;
    const int n0 = blockIdx.y * 64;
    const int tid = threadIdx.x;
    const int r  = tid >> 4;
    const int c4 = (tid & 15) * 4;
    #pragma unroll
    for (int i = 0; i < 4; ++i) {
        float4 v = *reinterpret_cast<const float4*>(&W[(size_t)(k0 + r + i * 16) * Dsz + n0 + c4]);
        Ls[r + i * 16][c4 + 0] = v.x;
        Ls[r + i * 16][c4 + 1] = v.y;
        Ls[r + i * 16][c4 + 2] = v.z;
        Ls[r + i * 16][c4 + 3] = v.w;
    }
    __syncthreads();
    #pragma unroll
    for (int i = 0; i < 4; ++i) {
        const int n = r + i * 16;
        bf16x4 o;
        o[0] = (bf16_t)Ls[c4 + 0][n];
        o[1] = (bf16_t)Ls[c4 + 1][n];
        o[2] = (bf16_t)Ls[c4 + 2][n];
        o[3] = (bf16_t)Ls[c4 + 3][n];
        *reinterpret_cast<bf16x4*>(&T[(size_t)(n0 + n) * Dsz + k0 + c4]) = o;
    }
}

// ---------------- chunked linear attention (fp32) ----------------
__global__ __launch_bounds__(256) void chunk_intra_kernel(
    const float* __restrict__ Qp, float* KO, const float* __restrict__ Vp,
    float* __restrict__ dS)
{
    const int bid = blockIdx.x;
    const int c  = bid & (NC - 1);
    const int bh = bid / NC;
    const int b = bh >> 4, h = bh & 15;
    const int tid = threadIdx.x;

    __shared__ float Qs[64][65], Ks[64][65], Vs[64][65];

    const size_t gbase = ((size_t)b * Lsz + (size_t)c * 64) * Dsz + h * Dh;

    {
        const int col = (tid & 15) * 4;
        const int rb  = tid >> 4;
        #pragma unroll
        for (int k = 0; k < 4; ++k) {
            const int row = rb + k * 16;
            const size_t ga = gbase + (size_t)row * Dsz + col;
            float4 q  = *reinterpret_cast<const float4*>(&Qp[ga]);
            float4 kk = *reinterpret_cast<const float4*>(&KO[ga]);
            float4 v  = *reinterpret_cast<const float4*>(&Vp[ga]);
            Qs[row][col] = q.x; Qs[row][col+1] = q.y; Qs[row][col+2] = q.z; Qs[row][col+3] = q.w;
            Ks[row][col] = kk.x; Ks[row][col+1] = kk.y; Ks[row][col+2] = kk.z; Ks[row][col+3] = kk.w;
            Vs[row][col] = v.x; Vs[row][col+1] = v.y; Vs[row][col+2] = v.z; Vs[row][col+3] = v.w;
        }
    }
    __syncthreads();

    const int r0 = (tid >> 4) * 4;
    const int c0 = (tid & 15) * 4;

    float p[4][4] = {};
    for (int d = 0; d < 64; ++d) {
        float qa[4], kb[4];
        #pragma unroll
        for (int a = 0; a < 4; ++a) qa[a] = Qs[r0 + a][d];
        #pragma unroll
        for (int bb = 0; bb < 4; ++bb) kb[bb] = Ks[c0 + bb][d];
        #pragma unroll
        for (int a = 0; a < 4; ++a)
            #pragma unroll
            for (int bb = 0; bb < 4; ++bb)
                p[a][bb] += qa[a] * kb[bb];
    }
    #pragma unroll
    for (int a = 0; a < 4; ++a)
        #pragma unroll
        for (int bb = 0; bb < 4; ++bb)
            if (r0 + a < c0 + bb) p[a][bb] = 0.f;

    float dt[4][4] = {};
    for (int j = 0; j < 64; ++j) {
        float ka[4], vb[4];
        #pragma unroll
        for (int a = 0; a < 4; ++a) ka[a] = Ks[j][r0 + a];
        #pragma unroll
        for (int bb = 0; bb < 4; ++bb) vb[bb] = Vs[j][c0 + bb];
        #pragma unroll
        for (int a = 0; a < 4; ++a)
            #pragma unroll
            for (int bb = 0; bb < 4; ++bb)
                dt[a][bb] += ka[a] * vb[bb];
    }
    __syncthreads();

    #pragma unroll
    for (int a = 0; a < 4; ++a)
        #pragma unroll
        for (int bb = 0; bb < 4; ++bb)
            Qs[r0 + a][c0 + bb] = p[a][bb];
    __syncthreads();

    float o[4][4] = {};
    for (int j = 0; j < 64; ++j) {
        float pa[4], vb[4];
        #pragma unroll
        for (int a = 0; a < 4; ++a) pa[a] = Qs[r0 + a][j];
        #pragma unroll
        for (int bb = 0; bb < 4; ++bb) vb[bb] = Vs[j][c0 + bb];
        #pragma unroll
        for (int a = 0; a < 4; ++a)
            #pragma unroll
            for (int bb = 0; bb < 4; ++bb)
                o[a][bb] += pa[a] * vb[bb];
    }

    const size_t sbase = ((size_t)bh * NC + c) * 4096;
    #pragma unroll
    for (int a = 0; a < 4; ++a) {
        float4 ov = make_float4(o[a][0], o[a][1], o[a][2], o[a][3]);
        float4 dv = make_float4(dt[a][0], dt[a][1], dt[a][2], dt[a][3]);
        *reinterpret_cast<float4*>(&KO[gbase + (size_t)(r0 + a) * Dsz + c0]) = ov;
        *reinterpret_cast<float4*>(&dS[sbase + (size_t)(r0 + a) * 64 + c0]) = dv;
    }
}

// in-place exclusive prefix over chunks; 512 blocks = (bh) x (16 slices of 256)
__global__ __launch_bounds__(256) void chunk_prefix_kernel(float* dS)
{
    const int g = blockIdx.x;
    const int bh = g >> 4;
    const int slice = g & 15;
    float* base = dS + (size_t)bh * NC * 4096 + slice * 256 + threadIdx.x;
    float acc = 0.f;
    #pragma unroll
    for (int c = 0; c < NC; ++c) {
        float v = base[(size_t)c * 4096];
        base[(size_t)c * 4096] = acc;
        acc += v;
    }
}

__global__ __launch_bounds__(256) void chunk_inter_kernel(
    const float* __restrict__ Qp, float* O, const float* __restrict__ S)
{
    const int bid = blockIdx.x;
    const int c  = bid & (NC - 1);
    const int bh = bid / NC;
    const int b = bh >> 4, h = bh & 15;
    const int tid = threadIdx.x;

    __shared__ float Qs[64][65], Ss[64][65];

    const size_t gbase = ((size_t)b * Lsz + (size_t)c * 64) * Dsz + h * Dh;
    const size_t sbase = ((size_t)bh * NC + c) * 4096;

    {
        const int col = (tid & 15) * 4;
        const int rb  = tid >> 4;
        #pragma unroll
        for (int k = 0; k < 4; ++k) {
            const int row = rb + k * 16;
            float4 q = *reinterpret_cast<const float4*>(&Qp[gbase + (size_t)row * Dsz + col]);
            float4 s = *reinterpret_cast<const float4*>(&S[sbase + (size_t)row * 64 + col]);
            Qs[row][col] = q.x; Qs[row][col+1] = q.y; Qs[row][col+2] = q.z; Qs[row][col+3] = q.w;
            Ss[row][col] = s.x; Ss[row][col+1] = s.y; Ss[row][col+2] = s.z; Ss[row][col+3] = s.w;
        }
    }
    __syncthreads();

    const int r0 = (tid >> 4) * 4;
    const int c0 = (tid & 15) * 4;

    float o[4][4] = {};
    for (int d = 0; d < 64; ++d) {
        float qa[4], sb[4];
        #pragma unroll
        for (int a = 0; a < 4; ++a) qa[a] = Qs[r0 + a][d];
        #pragma unroll
        for (int bb = 0; bb < 4; ++bb) sb[bb] = Ss[d][c0 + bb];
        #pragma unroll
        for (int a = 0; a < 4; ++a)
            #pragma unroll
            for (int bb = 0; bb < 4; ++bb)
                o[a][bb] += qa[a] * sb[bb];
    }

    #pragma unroll
    for (int a = 0; a < 4; ++a) {
        float* dst = &O[gbase + (size_t)(r0 + a) * Dsz + c0];
        float4 cur = *reinterpret_cast<const float4*>(dst);
        cur.x += o[a][0]; cur.y += o[a][1]; cur.z += o[a][2]; cur.w += o[a][3];
        *reinterpret_cast<float4*>(dst) = cur;
    }
}

// elementwise: k2 over Z, q2 over Q, E = x[l+1]-O1[l] -> E
__global__ __launch_bounds__(256) void ew_kernel(
    const float* __restrict__ x, const float* __restrict__ O1,
    float* Z, float* Q, float* E)
{
    const int i4 = blockIdx.x * 256 + threadIdx.x;
    const size_t fi = (size_t)i4 * 4;
    const int l = (int)((fi >> 10) & (Lsz - 1));

    float4 z = *reinterpret_cast<const float4*>(&Z[fi]);
    z.x = 1.f / (1.f + __expf(-z.x * 0.000625f));
    z.y = 1.f / (1.f + __expf(-z.y * 0.000625f));
    z.z = 1.f / (1.f + __expf(-z.z * 0.000625f));
    z.w = 1.f / (1.f + __expf(-z.w * 0.000625f));
    *reinterpret_cast<float4*>(&Z[fi]) = z;

    float4 q = *reinterpret_cast<const float4*>(&Q[fi]);
    q.x = (q.x >= 0.f ? 0.02f * q.x : q.x) * 0.125f;
    q.y = (q.y >= 0.f ? 0.02f * q.y : q.y) * 0.125f;
    q.z = (q.z >= 0.f ? 0.02f * q.z : q.z) * 0.125f;
    q.w = (q.w >= 0.f ? 0.02f * q.w : q.w) * 0.125f;
    *reinterpret_cast<float4*>(&Q[fi]) = q;

    float4 e;
    if (l == Lsz - 1) {
        e = make_float4(0.f, 0.f, 0.f, 0.f);
    } else {
        float4 xv = *reinterpret_cast<const float4*>(&x[fi + Dsz]);
        float4 ov = *reinterpret_cast<const float4*>(&O1[fi]);
        e = make_float4(xv.x - ov.x, xv.y - ov.y, xv.z - ov.z, xv.w - ov.w);
    }
    *reinterpret_cast<float4*>(&E[fi]) = e;
}

// yb = bf16(O1[l] + (l>0 ? O2[l-1] : 0))
__global__ __launch_bounds__(256) void combine_kernel(
    const float* __restrict__ O1, const float* __restrict__ O2, bf16_t* __restrict__ yb)
{
    const size_t fi = ((size_t)blockIdx.x * 256 + threadIdx.x) * 4;
    const int l = (int)((fi >> 10) & (Lsz - 1));
    float4 a = *reinterpret_cast<const float4*>(&O1[fi]);
    if (l > 0) {
        float4 b2 = *reinterpret_cast<const float4*>(&O2[fi - Dsz]);
        a.x += b2.x; a.y += b2.y; a.z += b2.z; a.w += b2.w;
    }
    bf16x4 o;
    o[0] = (bf16_t)a.x; o[1] = (bf16_t)a.y; o[2] = (bf16_t)a.z; o[3] = (bf16_t)a.w;
    *reinterpret_cast<bf16x4*>(&yb[fi]) = o;
}

extern "C" void kernel_launch(void* const* d_in, const int* in_sizes, int n_in,
                              void* d_out, int out_size, void* d_ws, size_t ws_size,
                              hipStream_t stream) {
    const float* x   = (const float*)d_in[0];
    const float* Wq  = (const float*)d_in[1];
    const float* bq  = (const float*)d_in[2];
    const float* Wk1 = (const float*)d_in[3];
    const float* bk1 = (const float*)d_in[4];
    const float* Wv  = (const float*)d_in[5];
    const float* bv  = (const float*)d_in[6];
    const float* Wk2 = (const float*)d_in[7];
    const float* bk2 = (const float*)d_in[8];
    const float* Wp  = (const float*)d_in[9];
    const float* bp  = (const float*)d_in[10];
    float* out = (float*)d_out;
    float* ws  = (float*)d_ws;

    const size_t mat = (size_t)Mtot * Dsz;   // 2M elements
    float* Qb  = ws;             // f32 Q -> q2
    float* Kb  = ws + mat;       // f32 K -> O1
    float* Vb  = ws + 2 * mat;   // f32 V -> E
    float* dSS = ws + 3 * mat;   // f32 chunk states (2M); later reused for yb
    bf16_t* xb = (bf16_t*)(ws + 4 * mat);            // bf16 x
    bf16_t* Wt = (bf16_t*)(ws + 4 * mat + mat / 2);  // 5 x (1M bf16), concatenated W^T
    bf16_t* T0 = Wt;
    bf16_t* T1 = Wt + 1048576;
    bf16_t* T2 = Wt + 2 * 1048576;
    bf16_t* T3 = Wt + 3 * 1048576;
    bf16_t* T4 = Wt + 4 * 1048576;
    float* Zb = out;             // d_out as f32 scratch for Z -> k2 -> O2
    bf16_t* yb = (bf16_t*)dSS;   // combine output (dSS dead by then)

    dim3 block(256);

    cast_kernel<<<dim3(2048), block, 0, stream>>>(x, xb);
    transpose_cast_kernel<<<dim3(16, 16, 5), block, 0, stream>>>(
        Wq, Wk1, Wv, Wk2, Wp, T0, T1, T2, T3, T4);

    // fused Q/K/V/Z projections: Bt = [Wq^T; Wk1^T; Wv^T; Wk2^T] (4096 x 1024)
    bgemm4_kernel<<<dim3(16, 32), block, 0, stream>>>(
        xb, Wt, Qb, Kb, Vb, Zb, bq, bk1, bv, bk2);

    const int nchunkblocks = Bsz * Hsz * NC;   // 512
    chunk_intra_kernel<<<dim3(nchunkblocks), block, 0, stream>>>(Qb, Kb, Vb, dSS);
    chunk_prefix_kernel<<<dim3(512), block, 0, stream>>>(dSS);
    chunk_inter_kernel<<<dim3(nchunkblocks), block, 0, stream>>>(Qb, Kb, dSS);   // Kb = O1
    ew_kernel<<<dim3(2048), block, 0, stream>>>(x, Kb, Zb, Qb, Vb);
    chunk_intra_kernel<<<dim3(nchunkblocks), block, 0, stream>>>(Qb, Zb, Vb, dSS);
    chunk_prefix_kernel<<<dim3(512), block, 0, stream>>>(dSS);
    chunk_inter_kernel<<<dim3(nchunkblocks), block, 0, stream>>>(Qb, Zb, dSS);   // Zb = O2

    combine_kernel<<<dim3(2048), block, 0, stream>>>(Kb, Zb, yb);
    bgemm4_kernel<<<dim3(16, 8), block, 0, stream>>>(
        yb, T4, out, out, out, out, bp, bp, bp, bp);
}

// Round 5
// 115.544 us; speedup vs baseline: 20.8505x; 1.3390x over previous
//
#include <hip/hip_runtime.h>
#include <hip/hip_bf16.h>
#include <math.h>

#define Bsz 2
#define Lsz 1024
#define Dsz 1024
#define Hsz 16
#define Dh 64
#define Mtot (Bsz*Lsz)   // 2048
#define NC (Lsz/64)      // 16 chunks per (b,h)
#define LPAD 72          // LDS row pitch (bf16 elems): 144B -> 2-way bank alias (free)

typedef __bf16 bf16_t;
typedef bf16_t bf16x8 __attribute__((ext_vector_type(8)));
typedef bf16_t bf16x4 __attribute__((ext_vector_type(4)));
typedef float f32x4v __attribute__((ext_vector_type(4)));

__device__ __forceinline__ void gload16(const void* g, void* l) {
    __builtin_amdgcn_global_load_lds(
        (const __attribute__((address_space(1))) unsigned int*)g,
        (__attribute__((address_space(3))) unsigned int*)l, 16, 0, 0);
}

// ---------------- bf16 MFMA GEMM, 2-phase double-buffer ----------------
// MODE 0: A(2048x1024) @ Wt[0..3]^T fused (grid.y=32); epilogue writes bf16
//         Q, q2=f(Q), K, V, k2=sigmoid(z*0.02/32) per projection p.
// MODE 1: A=yb @ Wt[4]^T (grid.y=8); epilogue writes f32 out + bias.
template<int MODE>
__global__ __launch_bounds__(256) void bgemm_kernel(
    const bf16_t* __restrict__ A, const bf16_t* __restrict__ Bt,
    const float* b0, const float* b1, const float* b2, const float* b3,
    bf16_t* Qo, bf16_t* q2o, bf16_t* Ko, bf16_t* Vo, bf16_t* k2o, float* Cout)
{
    __shared__ __align__(16) bf16_t As[2][4096];
    __shared__ __align__(16) bf16_t Bs[2][4096];
    const int tid  = threadIdx.x;
    const int lane = tid & 63;
    const int wid  = tid >> 6;
    const int row0  = blockIdx.x * 128;
    const int col0g = blockIdx.y * 128;
    const int p    = col0g >> 10;
    const int col0 = col0g & 1023;
    const int wr = (wid >> 1) * 64;
    const int wc = (wid & 1) * 64;

    const int srow = tid >> 2;
    const int scol = tid & 3;
    const int ssw  = (srow & 3) ^ ((srow >> 2) & 3);
    const int scol_sw = scol ^ ssw;
    const bf16_t* gA0 = A  + (size_t)(row0 + srow)       * 1024 + scol_sw * 8;
    const bf16_t* gA1 = A  + (size_t)(row0 + srow + 64)  * 1024 + scol_sw * 8;
    const bf16_t* gB0 = Bt + (size_t)(col0g + srow)      * 1024 + scol_sw * 8;
    const bf16_t* gB1 = Bt + (size_t)(col0g + srow + 64) * 1024 + scol_sw * 8;

    const int laneRow = lane & 15;
    const int kblk = lane >> 4;
    const int swz = (kblk ^ (laneRow & 3) ^ ((laneRow >> 2) & 3)) & 3;
    const int aoff = (wr + laneRow) * 32 + swz * 8;
    const int boff = (wc + laneRow) * 32 + swz * 8;

    f32x4v acc[4][4];
    #pragma unroll
    for (int i = 0; i < 4; ++i)
        #pragma unroll
        for (int j = 0; j < 4; ++j)
            acc[i][j] = (f32x4v){0.f, 0.f, 0.f, 0.f};

    gload16(gA0, &As[0][tid * 8]);
    gload16(gA1, &As[0][(tid + 256) * 8]);
    gload16(gB0, &Bs[0][tid * 8]);
    gload16(gB1, &Bs[0][(tid + 256) * 8]);
    gA0 += 32; gA1 += 32; gB0 += 32; gB1 += 32;
    asm volatile("s_waitcnt vmcnt(0)" ::: "memory");
    __builtin_amdgcn_s_barrier();

    int cur = 0;
    for (int k0 = 0; k0 < 1024; k0 += 32) {
        if (k0 + 32 < 1024) {
            const int nxt = cur ^ 1;
            gload16(gA0, &As[nxt][tid * 8]);
            gload16(gA1, &As[nxt][(tid + 256) * 8]);
            gload16(gB0, &Bs[nxt][tid * 8]);
            gload16(gB1, &Bs[nxt][(tid + 256) * 8]);
            gA0 += 32; gA1 += 32; gB0 += 32; gB1 += 32;
        }
        bf16x8 af[4], bfr[4];
        #pragma unroll
        for (int f = 0; f < 4; ++f) {
            af[f]  = *reinterpret_cast<const bf16x8*>(&As[cur][aoff + f * 512]);
            bfr[f] = *reinterpret_cast<const bf16x8*>(&Bs[cur][boff + f * 512]);
        }
        #pragma unroll
        for (int i = 0; i < 4; ++i)
            #pragma unroll
            for (int j = 0; j < 4; ++j)
                acc[i][j] = __builtin_amdgcn_mfma_f32_16x16x32_bf16(af[i], bfr[j], acc[i][j], 0, 0, 0);
        asm volatile("s_waitcnt vmcnt(0)" ::: "memory");
        __builtin_amdgcn_s_barrier();
        cur ^= 1;
    }

    const int crowb = row0 + wr + kblk * 4;
    const int ccolb = col0 + wc + laneRow;
    const float* bias = (MODE == 1) ? b0 : (p == 0) ? b0 : (p == 1) ? b1 : (p == 2) ? b2 : b3;
    float bv[4];
    #pragma unroll
    for (int j = 0; j < 4; ++j) bv[j] = bias[ccolb + j * 16];
    #pragma unroll
    for (int i = 0; i < 4; ++i)
        #pragma unroll
        for (int j = 0; j < 4; ++j)
            #pragma unroll
            for (int e = 0; e < 4; ++e) {
                const float val = acc[i][j][e] + bv[j];
                const size_t idx = (size_t)(crowb + i * 16 + e) * 1024 + ccolb + j * 16;
                if (MODE == 1) {
                    Cout[idx] = val;
                } else if (p == 0) {
                    Qo[idx]  = (bf16_t)val;
                    q2o[idx] = (bf16_t)((val >= 0.f ? 0.02f * val : val) * 0.125f);
                } else if (p == 1) {
                    Ko[idx] = (bf16_t)val;
                } else if (p == 2) {
                    Vo[idx] = (bf16_t)val;
                } else {
                    k2o[idx] = (bf16_t)(1.f / (1.f + __expf(-val * 0.000625f)));
                }
            }
}

// ---------------- prep: 5x W transpose-cast (z<5) + x cast (z==5) ----------------
__global__ __launch_bounds__(256) void prep_kernel(
    const float* __restrict__ x, bf16_t* __restrict__ xb,
    const float* __restrict__ W0, const float* __restrict__ W1,
    const float* __restrict__ W2, const float* __restrict__ W3,
    const float* __restrict__ W4, bf16_t* __restrict__ Wt)
{
    const int z = blockIdx.z;
    const int tid = threadIdx.x;
    if (z == 5) {
        const int lin = blockIdx.y * 16 + blockIdx.x;   // 0..255
        #pragma unroll
        for (int u = 0; u < 8; ++u) {
            const size_t s = (size_t)lin * 2048 + u * 256 + tid;
            float4 v = *reinterpret_cast<const float4*>(&x[s * 4]);
            bf16x4 o;
            o[0] = (bf16_t)v.x; o[1] = (bf16_t)v.y; o[2] = (bf16_t)v.z; o[3] = (bf16_t)v.w;
            *reinterpret_cast<bf16x4*>(&xb[s * 4]) = o;
        }
        return;
    }
    const float* W = (z == 0) ? W0 : (z == 1) ? W1 : (z == 2) ? W2 : (z == 3) ? W3 : W4;
    bf16_t* T = Wt + (size_t)z * 1048576;

    __shared__ float Ls[64][65];
    const int k0 = blockIdx.x * 64;
    const int n0 = blockIdx.y * 64;
    const int r  = tid >> 4;
    const int c4 = (tid & 15) * 4;
    #pragma unroll
    for (int i = 0; i < 4; ++i) {
        float4 v = *reinterpret_cast<const float4*>(&W[(size_t)(k0 + r + i * 16) * Dsz + n0 + c4]);
        Ls[r + i * 16][c4 + 0] = v.x;
        Ls[r + i * 16][c4 + 1] = v.y;
        Ls[r + i * 16][c4 + 2] = v.z;
        Ls[r + i * 16][c4 + 3] = v.w;
    }
    __syncthreads();
    #pragma unroll
    for (int i = 0; i < 4; ++i) {
        const int n = r + i * 16;
        bf16x4 o;
        o[0] = (bf16_t)Ls[c4 + 0][n];
        o[1] = (bf16_t)Ls[c4 + 1][n];
        o[2] = (bf16_t)Ls[c4 + 2][n];
        o[3] = (bf16_t)Ls[c4 + 3][n];
        *reinterpret_cast<bf16x4*>(&T[(size_t)(n0 + n) * Dsz + k0 + c4]) = o;
    }
}

// ---------------- MFMA chunk intra: P=A.K^T (causal), dT^T=V^T.K, Oi=P.V ----------------
// A,Kp,Vp: bf16 (B,L,D). Oi: f32 (B,L,D). dT: f32 [bh][c][e][d] (TRANSPOSED state).
__global__ __launch_bounds__(256) void chunk_intra_kernel(
    const bf16_t* __restrict__ Ap, const bf16_t* __restrict__ Kp,
    const bf16_t* __restrict__ Vp, float* __restrict__ Oi, float* __restrict__ dT)
{
    __shared__ __align__(16) bf16_t sQ[64 * LPAD];
    __shared__ __align__(16) bf16_t sK[64 * LPAD];
    __shared__ __align__(16) bf16_t sKt[64 * LPAD];
    __shared__ __align__(16) bf16_t sVt[64 * LPAD];
    __shared__ __align__(16) bf16_t sP[64 * LPAD];

    const int bid = blockIdx.x;
    const int c  = bid & (NC - 1);
    const int bh = bid >> 4;
    const int b = bh >> 4, h = bh & 15;
    const int tid = threadIdx.x;
    const size_t gbase = ((size_t)b * Lsz + (size_t)c * 64) * Dsz + h * Dh;

    // stage: Q,K row-major; Kt,Vt transposed
    #pragma unroll
    for (int cc = tid; cc < 512; cc += 256) {
        const int j = cc >> 3;
        const int d0 = (cc & 7) * 8;
        const size_t g = gbase + (size_t)j * 1024 + d0;
        bf16x8 qv = *reinterpret_cast<const bf16x8*>(&Ap[g]);
        bf16x8 kv = *reinterpret_cast<const bf16x8*>(&Kp[g]);
        bf16x8 vv = *reinterpret_cast<const bf16x8*>(&Vp[g]);
        *reinterpret_cast<bf16x8*>(&sQ[j * LPAD + d0]) = qv;
        *reinterpret_cast<bf16x8*>(&sK[j * LPAD + d0]) = kv;
        #pragma unroll
        for (int i = 0; i < 8; ++i) {
            sKt[(d0 + i) * LPAD + j] = kv[i];
            sVt[(d0 + i) * LPAD + j] = vv[i];
        }
    }
    __syncthreads();

    const int w = tid >> 6;
    const int lane = tid & 63;
    const int lr = lane & 15;
    const int kb = lane >> 4;
    const int m0 = w * 16;

    // P = Q.K^T (A-frag: sQ rows; B-frag: sK rows), causal mask j<=i
    f32x4v accp[4];
    #pragma unroll
    for (int n = 0; n < 4; ++n) accp[n] = (f32x4v){0.f, 0.f, 0.f, 0.f};
    #pragma unroll
    for (int kk = 0; kk < 2; ++kk) {
        bf16x8 a = *reinterpret_cast<const bf16x8*>(&sQ[(m0 + lr) * LPAD + kk * 32 + kb * 8]);
        #pragma unroll
        for (int n = 0; n < 4; ++n) {
            bf16x8 bb = *reinterpret_cast<const bf16x8*>(&sK[(n * 16 + lr) * LPAD + kk * 32 + kb * 8]);
            accp[n] = __builtin_amdgcn_mfma_f32_16x16x32_bf16(a, bb, accp[n], 0, 0, 0);
        }
    }
    // dT[e][d] = sum_j V[j][e] K[j][d]  (A-frag: sVt rows; B-frag: sKt rows)
    f32x4v acct[4];
    #pragma unroll
    for (int n = 0; n < 4; ++n) acct[n] = (f32x4v){0.f, 0.f, 0.f, 0.f};
    #pragma unroll
    for (int kk = 0; kk < 2; ++kk) {
        bf16x8 a = *reinterpret_cast<const bf16x8*>(&sVt[(m0 + lr) * LPAD + kk * 32 + kb * 8]);
        #pragma unroll
        for (int n = 0; n < 4; ++n) {
            bf16x8 bb = *reinterpret_cast<const bf16x8*>(&sKt[(n * 16 + lr) * LPAD + kk * 32 + kb * 8]);
            acct[n] = __builtin_amdgcn_mfma_f32_16x16x32_bf16(a, bb, acct[n], 0, 0, 0);
        }
    }

    // write dT (f32 global) + masked P -> sP (bf16)
    const size_t tbase = (size_t)bid * 4096;
    #pragma unroll
    for (int n = 0; n < 4; ++n)
        #pragma unroll
        for (int e = 0; e < 4; ++e) {
            const int r = m0 + kb * 4 + e;
            const int col = n * 16 + lr;
            dT[tbase + (size_t)r * 64 + col] = acct[n][e];
            float pv = (col <= r) ? accp[n][e] : 0.f;
            sP[r * LPAD + col] = (bf16_t)pv;
        }
    __syncthreads();

    // Oi = P.V (A-frag: sP rows; B-frag: sVt rows)
    f32x4v acco[4];
    #pragma unroll
    for (int n = 0; n < 4; ++n) acco[n] = (f32x4v){0.f, 0.f, 0.f, 0.f};
    #pragma unroll
    for (int kk = 0; kk < 2; ++kk) {
        bf16x8 a = *reinterpret_cast<const bf16x8*>(&sP[(m0 + lr) * LPAD + kk * 32 + kb * 8]);
        #pragma unroll
        for (int n = 0; n < 4; ++n) {
            bf16x8 bb = *reinterpret_cast<const bf16x8*>(&sVt[(n * 16 + lr) * LPAD + kk * 32 + kb * 8]);
            acco[n] = __builtin_amdgcn_mfma_f32_16x16x32_bf16(a, bb, acco[n], 0, 0, 0);
        }
    }
    #pragma unroll
    for (int n = 0; n < 4; ++n)
        #pragma unroll
        for (int e = 0; e < 4; ++e)
            Oi[gbase + (size_t)(m0 + kb * 4 + e) * 1024 + n * 16 + lr] = acco[n][e];
}

// in-place exclusive prefix over chunks; 512 blocks = (bh) x (16 slices of 256)
__global__ __launch_bounds__(256) void chunk_prefix_kernel(float* dT)
{
    const int g = blockIdx.x;
    const int bh = g >> 4;
    const int slice = g & 15;
    float* base = dT + (size_t)bh * NC * 4096 + slice * 256 + threadIdx.x;
    float acc = 0.f;
    #pragma unroll
    for (int c = 0; c < NC; ++c) {
        float v = base[(size_t)c * 4096];
        base[(size_t)c * 4096] = acc;
        acc += v;
    }
}

// ---------------- MFMA chunk inter + fused epilogues ----------------
// O[i][e] = Oi[i][e] + sum_d A[i][d] * S[d][e], with T=S^T stored [e][d].
// BR1: O1out=O (f32); ebout E[l] = x[l+1]-O1[l] (bf16, l==1023 -> 0); xin = x (f32)
// BR2: ebout yb: yb[l+1] = bf16(O1[l+1] + O2[l]); yb[0] = bf16(O1[0]); xin = O1 (f32)
template<int BR>
__global__ __launch_bounds__(256) void chunk_inter_kernel(
    const bf16_t* __restrict__ Ap, const float* __restrict__ T,
    const float* __restrict__ Oi, const float* __restrict__ xin,
    float* __restrict__ O1out, bf16_t* __restrict__ ebout)
{
    __shared__ __align__(16) bf16_t sA[64 * LPAD];
    __shared__ __align__(16) bf16_t sT[64 * LPAD];

    const int bid = blockIdx.x;
    const int c  = bid & (NC - 1);
    const int bh = bid >> 4;
    const int b = bh >> 4, h = bh & 15;
    const int tid = threadIdx.x;
    const size_t gbase = ((size_t)b * Lsz + (size_t)c * 64) * Dsz + h * Dh;

    #pragma unroll
    for (int cc = tid; cc < 512; cc += 256) {
        const int j = cc >> 3;
        const int d0 = (cc & 7) * 8;
        bf16x8 av = *reinterpret_cast<const bf16x8*>(&Ap[gbase + (size_t)j * 1024 + d0]);
        *reinterpret_cast<bf16x8*>(&sA[j * LPAD + d0]) = av;
    }
    {
        const size_t tb = (size_t)bid * 4096;
        const int row = tid >> 2;
        const int c16 = (tid & 3) * 16;
        float4 v0 = *reinterpret_cast<const float4*>(&T[tb + (size_t)row * 64 + c16]);
        float4 v1 = *reinterpret_cast<const float4*>(&T[tb + (size_t)row * 64 + c16 + 4]);
        float4 v2 = *reinterpret_cast<const float4*>(&T[tb + (size_t)row * 64 + c16 + 8]);
        float4 v3 = *reinterpret_cast<const float4*>(&T[tb + (size_t)row * 64 + c16 + 12]);
        bf16x8 o0, o1;
        o0[0] = (bf16_t)v0.x; o0[1] = (bf16_t)v0.y; o0[2] = (bf16_t)v0.z; o0[3] = (bf16_t)v0.w;
        o0[4] = (bf16_t)v1.x; o0[5] = (bf16_t)v1.y; o0[6] = (bf16_t)v1.z; o0[7] = (bf16_t)v1.w;
        o1[0] = (bf16_t)v2.x; o1[1] = (bf16_t)v2.y; o1[2] = (bf16_t)v2.z; o1[3] = (bf16_t)v2.w;
        o1[4] = (bf16_t)v3.x; o1[5] = (bf16_t)v3.y; o1[6] = (bf16_t)v3.z; o1[7] = (bf16_t)v3.w;
        *reinterpret_cast<bf16x8*>(&sT[row * LPAD + c16]) = o0;
        *reinterpret_cast<bf16x8*>(&sT[row * LPAD + c16 + 8]) = o1;
    }
    __syncthreads();

    const int w = tid >> 6;
    const int lane = tid & 63;
    const int lr = lane & 15;
    const int kb = lane >> 4;
    const int m0 = w * 16;

    f32x4v acc[4];
    #pragma unroll
    for (int n = 0; n < 4; ++n) acc[n] = (f32x4v){0.f, 0.f, 0.f, 0.f};
    #pragma unroll
    for (int kk = 0; kk < 2; ++kk) {
        bf16x8 a = *reinterpret_cast<const bf16x8*>(&sA[(m0 + lr) * LPAD + kk * 32 + kb * 8]);
        #pragma unroll
        for (int n = 0; n < 4; ++n) {
            bf16x8 bb = *reinterpret_cast<const bf16x8*>(&sT[(n * 16 + lr) * LPAD + kk * 32 + kb * 8]);
            acc[n] = __builtin_amdgcn_mfma_f32_16x16x32_bf16(a, bb, acc[n], 0, 0, 0);
        }
    }

    #pragma unroll
    for (int n = 0; n < 4; ++n)
        #pragma unroll
        for (int e = 0; e < 4; ++e) {
            const int iLoc = m0 + kb * 4 + e;
            const int lglob = c * 64 + iLoc;
            const size_t idx = gbase + (size_t)iLoc * 1024 + n * 16 + lr;
            const float val = acc[n][e] + Oi[idx];
            if (BR == 1) {
                O1out[idx] = val;
                float ev = 0.f;
                if (lglob < Lsz - 1) ev = xin[idx + 1024] - val;
                ebout[idx] = (bf16_t)ev;
            } else {
                if (lglob < Lsz - 1) ebout[idx + 1024] = (bf16_t)(xin[idx + 1024] + val);
                if (lglob == 0)      ebout[idx] = (bf16_t)(xin[idx]);
            }
        }
}

extern "C" void kernel_launch(void* const* d_in, const int* in_sizes, int n_in,
                              void* d_out, int out_size, void* d_ws, size_t ws_size,
                              hipStream_t stream) {
    const float* x   = (const float*)d_in[0];
    const float* Wq  = (const float*)d_in[1];
    const float* bq  = (const float*)d_in[2];
    const float* Wk1 = (const float*)d_in[3];
    const float* bk1 = (const float*)d_in[4];
    const float* Wv  = (const float*)d_in[5];
    const float* bv  = (const float*)d_in[6];
    const float* Wk2 = (const float*)d_in[7];
    const float* bk2 = (const float*)d_in[8];
    const float* Wp  = (const float*)d_in[9];
    const float* bp  = (const float*)d_in[10];
    float* out = (float*)d_out;
    float* ws  = (float*)d_ws;

    const size_t mat = (size_t)Mtot * Dsz;   // 2M elements
    float*  O1  = ws;                         // f32 (B,L,D)
    float*  Oib = ws + mat;                   // f32 intra out (both branches)
    float*  dT  = ws + 2 * mat;               // f32 states [bh][c][4096]
    bf16_t* xb  = (bf16_t*)(ws + 3 * mat);    // 2M bf16 = 1M f32
    bf16_t* Wt  = (bf16_t*)(ws + 3 * mat + mat / 2);   // 5 x 1M bf16 = 2.5M f32
    float*  b16base = ws + 3 * mat + 3 * mat; // = ws + 6M
    bf16_t* Qr  = (bf16_t*)(b16base);
    bf16_t* q2  = (bf16_t*)(b16base + mat / 2);
    bf16_t* Kb  = (bf16_t*)(b16base + 2 * (mat / 2));
    bf16_t* Vb  = (bf16_t*)(b16base + 3 * (mat / 2));
    bf16_t* k2  = (bf16_t*)(b16base + 4 * (mat / 2));
    bf16_t* Eb  = (bf16_t*)(b16base + 5 * (mat / 2));
    bf16_t* yb  = (bf16_t*)(b16base + 6 * (mat / 2));

    dim3 block(256);

    prep_kernel<<<dim3(16, 16, 6), block, 0, stream>>>(x, xb, Wq, Wk1, Wv, Wk2, Wp, Wt);

    bgemm_kernel<0><<<dim3(16, 32), block, 0, stream>>>(
        xb, Wt, bq, bk1, bv, bk2, Qr, q2, Kb, Vb, k2, nullptr);

    // branch 1
    chunk_intra_kernel<<<dim3(512), block, 0, stream>>>(Qr, Kb, Vb, Oib, dT);
    chunk_prefix_kernel<<<dim3(512), block, 0, stream>>>(dT);
    chunk_inter_kernel<1><<<dim3(512), block, 0, stream>>>(Qr, dT, Oib, x, O1, Eb);
    // branch 2
    chunk_intra_kernel<<<dim3(512), block, 0, stream>>>(q2, k2, Eb, Oib, dT);
    chunk_prefix_kernel<<<dim3(512), block, 0, stream>>>(dT);
    chunk_inter_kernel<2><<<dim3(512), block, 0, stream>>>(q2, dT, Oib, O1, nullptr, yb);

    bgemm_kernel<1><<<dim3(16, 8), block, 0, stream>>>(
        yb, Wt + 4 * 1048576, bp, nullptr, nullptr, nullptr,
        nullptr, nullptr, nullptr, nullptr, nullptr, out);
}